// Round 14
// baseline (192.018 us; speedup 1.0000x reference)
//
#include <hip/hip_runtime.h>

// Chamfer loss: pred (2048,8,3) vs gt (2048,8,3) fp32. N=16384 pts/side.
// out = mean(min_m d) + mean(min_n d); 8-corner group-mean == global mean.
//
// R17: MINIMIZE TOTAL PIPE-CYCLES under the standing clock-throttle
// theory (post-fill DPM: both pipes consistently imply ~0.7GHz eff;
// survived VALU/spill/L2 surgery R8-R16; L2 fix bought only 4us).
//  - BIDIRECTIONAL single pass again: one S=pred.gt^T serves row-min AND
//    col-min -> MFMA 10K->5K cyc/SIMD vs R16. VALU only +cmax merges
//    (8 VALU per MFMA pair) -> new bound ~9.2K cyc/SIMD.
//  - builtin MFMA (no inline asm): compiler schedules MFMA latency and
//    interleaves the max3 consumers - drops R15/R16's ~19 wave-serial
//    nop cycles per 2 MFMAs (marginal at 4 waves/SIMD duty).
//  - per-wave: af[8]+rmax[8] persistent (whole kernel), cmax[8] flushed
//    per 8-tile chunk (2 shfl/tile, amortized over 64 MFMAs).
//  - B shared via 8KB double-buffered LDS chunks (R16-verified), 2
//    barriers/chunk; col partials combined across waves in LDS colacc.
//  - verified invariants: bf16 3-way-split K-packing (absmax 0.0 since
//    R5), kg-major fragment layout, DPP row flush, coalesced partial
//    stores, no hot-loop atomics, separate 32-block reduce (R5 lesson:
//    never single-block tail).
// Falsification: bidi >=30us w/ clean counters -> throttle confirmed,
// declare harness floor next round.

#define NPTS   16384
#define BLOCK  256            // 4 waves
#define XW     128            // x-points per wave (8 tiles, af in 32 VGPR)
#define XCH    512            // x-points per block (32 tiles)
#define NXB    (NPTS / XCH)   // 32
#define YRNG   512            // y-points per block (32 tiles)
#define NYR    (NPTS / YRNG)  // 32
#define CHT    8              // y-tiles per LDS chunk (8 KB)
#define NCH    (YRNG / (CHT * 16))  // 4 chunks
#define ONEBF  0x3F80         // bf16 1.0

// ws: [0,1MB) Ppa | [1,2MB) Pgb | [2MB,6MB) part[64][NPTS] f32
//   slices 0..31  = row partials (pred mins), id = yr
//   slices 32..63 = col partials (gt mins),   id = 32+xb
#define WS_PGB  (1u << 20)
#define WS_PART (2u << 20)
#define NROWSL  NYR           // 32
#define NCOLSL  NXB           // 32

typedef __attribute__((ext_vector_type(8))) short bf16x8;
typedef __attribute__((ext_vector_type(4))) float f32x4;

__device__ inline unsigned short f2bf(float f) {  // fp32 -> bf16 RNE
    unsigned int u = __float_as_uint(f);
    return (unsigned short)((u + 0x7FFFu + ((u >> 16) & 1u)) >> 16);
}
__device__ inline float bf2f(unsigned short h) {
    return __uint_as_float((unsigned int)h << 16);
}
__device__ inline void split3(float v, unsigned short* s) {
    unsigned short h = f2bf(v);  float r = v - bf2f(h);
    unsigned short m = f2bf(r);  r -= bf2f(m);
    s[0] = h; s[1] = m; s[2] = f2bf(r);
}

// K-slot map (identical order on A and B rows => lane->K bijection cancels):
//   s=c*3+d, c<6: cross combos (i,j)=(h,h)(h,m)(m,h)(h,l)(m,m)(l,h)
//   s=18..20: a=split3(-|p|^2/2), b=1 ; s=21..23: a=1, b=split3(-|p|^2/2)
//   s=24..31: 0   => S[r][c] = x.y - |x|^2/2 - |y|^2/2 = -d2/2
__device__ inline void build_rows(const float p[3], unsigned short* a,
                                  unsigned short* b) {
    const int CI[6] = {0, 0, 1, 0, 1, 2};
    const int CJ[6] = {0, 1, 0, 2, 1, 0};
    unsigned short xs[3][3], nn[3], t[3];
#pragma unroll
    for (int d = 0; d < 3; ++d) {
        split3(p[d], t);
        xs[0][d] = t[0]; xs[1][d] = t[1]; xs[2][d] = t[2];
    }
    split3(-0.5f * (p[0]*p[0] + p[1]*p[1] + p[2]*p[2]), nn);
#pragma unroll
    for (int c = 0; c < 6; ++c)
#pragma unroll
        for (int d = 0; d < 3; ++d) {
            a[c*3+d] = xs[CI[c]][d];
            b[c*3+d] = xs[CJ[c]][d];
        }
#pragma unroll
    for (int k = 0; k < 3; ++k) {
        a[18+k] = nn[k];  b[18+k] = ONEBF;
        a[21+k] = ONEBF;  b[21+k] = nn[k];
    }
#pragma unroll
    for (int k = 24; k < 32; ++k) { a[k] = 0; b[k] = 0; }
}

// Fragment-swizzled store (R12-verified): point i, K-chunk kg -> uint4 slot
// (i/16)*64 + kg*16 + (i%16); lane (col,kg) reads frag at slot
// tile*64 + kg*16 + col -> wave reads a contiguous 1KB line per instr.
__device__ inline void store_row_swz(uint4* dst4, int i, const unsigned short* s) {
    unsigned int w[16];
#pragma unroll
    for (int k = 0; k < 16; ++k)
        w[k] = (unsigned int)s[2*k] | ((unsigned int)s[2*k+1] << 16);
    const int base = (i >> 4) * 64 + (i & 15);
#pragma unroll
    for (int kgc = 0; kgc < 4; ++kgc)
        dst4[base + kgc * 16] = make_uint4(w[4*kgc], w[4*kgc+1],
                                           w[4*kgc+2], w[4*kgc+3]);
}

__global__ __launch_bounds__(256) void pack_points(
        const float* __restrict__ pred, const float* __restrict__ gt,
        unsigned short* __restrict__ Ppa, unsigned short* __restrict__ Pgb,
        float* __restrict__ out) {
    const int i = blockIdx.x * 256 + threadIdx.x;
    if (i == 0) out[0] = 0.0f;  // replaces a memset dispatch
    if (i >= NPTS) return;
    float p[3] = {pred[3*i], pred[3*i+1], pred[3*i+2]};
    float q[3] = {gt[3*i],   gt[3*i+1],   gt[3*i+2]};
    unsigned short ra[32], rb[32];
    build_rows(p, ra, rb);
    store_row_swz(reinterpret_cast<uint4*>(Ppa), i, ra);  // pred = A (rows)
    build_rows(q, ra, rb);
    store_row_swz(reinterpret_cast<uint4*>(Pgb), i, rb);  // gt = B (cols)
}

// DPP rotate-max within 16-lane rows (VALU pipe; verified R6-R16).
template <int CTRL>
__device__ inline float rormax(float v) {
    int t = __builtin_amdgcn_update_dpp(0, __float_as_int(v), CTRL, 0xF, 0xF,
                                        false);
    return fmaxf(v, __int_as_float(t));
}

__global__ __launch_bounds__(BLOCK, 1) void chamfer_bidi(
        const unsigned short* __restrict__ Ppa,
        const unsigned short* __restrict__ Pgb,
        float* __restrict__ part) {
    const int yr = blockIdx.x;   // fastest-varying -> XCD = yr % 8 (B pin)
    const int xb = blockIdx.y;
    const int tid = threadIdx.x;
    const int lane = tid & 63, w = tid >> 6;
    const int col = lane & 15, kg = lane >> 4;
    const int frag = kg * 16 + col;      // uint4 index of this lane's frag

    __shared__ uint4 buf[2][CHT * 64];   // 2 x 8 KB B double-buffer
    __shared__ float rowacc[XCH];        // 2 KB
    __shared__ float colacc[4][YRNG];    // 8 KB

    // A-frags: wave's 8 x-tiles (each load = contiguous 1KB line)
    const uint4* ap = reinterpret_cast<const uint4*>(Ppa);
    const int tile0 = xb * 32 + w * 8;
    bf16x8 af[8];
#pragma unroll
    for (int xi = 0; xi < 8; ++xi)
        af[xi] = *reinterpret_cast<const bf16x8*>(&ap[(tile0 + xi) * 64 + frag]);

    f32x4 rmax[8];
#pragma unroll
    for (int xi = 0; xi < 8; ++xi)
        rmax[xi] = (f32x4){-3.0e38f, -3.0e38f, -3.0e38f, -3.0e38f};
    float cmax[CHT];
#pragma unroll
    for (int yt = 0; yt < CHT; ++yt) cmax[yt] = -3.0e38f;

    const f32x4 z4 = {0.0f, 0.0f, 0.0f, 0.0f};

    // B chunks: block's 4 waves SHARE each 8KB chunk via LDS.
    const uint4* bp = reinterpret_cast<const uint4*>(Pgb) + (size_t)yr * 2048;
    uint4 s0 = bp[tid];                  // prologue: chunk 0 into regs
    uint4 s1 = bp[256 + tid];

#pragma unroll 1
    for (int c = 0; c < NCH; ++c) {
        buf[c & 1][tid]       = s0;
        buf[c & 1][256 + tid] = s1;
        __syncthreads();                 // chunk staged
        if (c + 1 < NCH) {               // issue next loads; L2 latency
            s0 = bp[(c + 1) * 512 + tid];        // hides under 256 MFMAs
            s1 = bp[(c + 1) * 512 + 256 + tid];
        }
        const uint4* bb = buf[c & 1];
#pragma unroll
        for (int t = 0; t < CHT; t += 2) {
            bf16x8 b0 = *reinterpret_cast<const bf16x8*>(&bb[(t + 0) * 64 + frag]);
            bf16x8 b1 = *reinterpret_cast<const bf16x8*>(&bb[(t + 1) * 64 + frag]);
#pragma unroll
            for (int xi = 0; xi < 8; ++xi) {
                f32x4 A = __builtin_amdgcn_mfma_f32_16x16x32_bf16(af[xi], b0, z4, 0, 0, 0);
                f32x4 B = __builtin_amdgcn_mfma_f32_16x16x32_bf16(af[xi], b1, z4, 0, 0, 0);
                // row-merge: 4 v_max3 per MFMA pair (persists whole kernel)
                rmax[xi].x = fmaxf(fmaxf(A.x, B.x), rmax[xi].x);
                rmax[xi].y = fmaxf(fmaxf(A.y, B.y), rmax[xi].y);
                rmax[xi].z = fmaxf(fmaxf(A.z, B.z), rmax[xi].z);
                rmax[xi].w = fmaxf(fmaxf(A.w, B.w), rmax[xi].w);
                // col-merge: 2 v_max3 per MFMA
                float ta = fmaxf(fmaxf(A.x, A.y), A.z);
                cmax[t]     = fmaxf(fmaxf(ta, A.w), cmax[t]);
                float tb = fmaxf(fmaxf(B.x, B.y), B.z);
                cmax[t + 1] = fmaxf(fmaxf(tb, B.w), cmax[t + 1]);
            }
        }
        // per-chunk col flush: 2 shfl/tile (over the 4 kg row-groups),
        // kg==0 lanes park in this wave's colacc row; reset cmax.
#pragma unroll
        for (int yt = 0; yt < CHT; ++yt) {
            float v = cmax[yt];
            v = fmaxf(v, __shfl_xor(v, 16, 64));
            v = fmaxf(v, __shfl_xor(v, 32, 64));
            if (kg == 0) colacc[w][c * 128 + yt * 16 + col] = v;
            cmax[yt] = -3.0e38f;
        }
        __syncthreads();                 // all reads of buf[c&1] done
    }

    // row flush ONCE per wave: DPP ror-max over 16 cols -> rowacc
#pragma unroll
    for (int xi = 0; xi < 8; ++xi) {
#pragma unroll
        for (int cc = 0; cc < 4; ++cc) {
            float v = rmax[xi][cc];
            v = rormax<0x121>(v);
            v = rormax<0x122>(v);
            v = rormax<0x124>(v);
            v = rormax<0x128>(v);
            if (col == 0)
                rowacc[w * XW + xi * 16 + kg * 4 + cc] = fmaxf(-2.0f * v, 0.0f);
        }
    }
    __syncthreads();

    // coalesced partial stores: rows (this block's x-range, slice yr),
    // cols (combine 4 waves' colacc, slice 32+xb)
    float* rdst = part + (size_t)yr * NPTS + xb * XCH;
    rdst[tid]       = rowacc[tid];
    rdst[256 + tid] = rowacc[256 + tid];
    float* cdst = part + (size_t)(NROWSL + xb) * NPTS + yr * YRNG;
#pragma unroll
    for (int j = 0; j < 2; ++j) {
        int idx = j * 256 + tid;
        float v = fmaxf(fmaxf(colacc[0][idx], colacc[1][idx]),
                        fmaxf(colacc[2][idx], colacc[3][idx]));
        cdst[idx] = fmaxf(-2.0f * v, 0.0f);
    }
}

__global__ __launch_bounds__(256) void chamfer_reduce(
        const float* __restrict__ part, float* __restrict__ out) {
    const int gid = blockIdx.x * 256 + threadIdx.x;  // 32 blocks x 256
    const int side = gid >> 12;                      // 4096 f32x4 per side
    const int idx4 = (gid & 4095) * 4;
    const float* base = part + (size_t)side * NROWSL * NPTS + idx4;
    float4 m = make_float4(3.0e38f, 3.0e38f, 3.0e38f, 3.0e38f);
#pragma unroll
    for (int c = 0; c < 32; ++c) {
        float4 v = *reinterpret_cast<const float4*>(base + (size_t)c * NPTS);
        m.x = fminf(m.x, v.x); m.y = fminf(m.y, v.y);
        m.z = fminf(m.z, v.z); m.w = fminf(m.w, v.w);
    }
    float s = sqrtf(m.x) + sqrtf(m.y) + sqrtf(m.z) + sqrtf(m.w);
#pragma unroll
    for (int o = 32; o > 0; o >>= 1)
        s += __shfl_down(s, o, 64);
    if ((threadIdx.x & 63) == 0)
        atomicAdd(out, s * (1.0f / (float)NPTS));
}

extern "C" void kernel_launch(void* const* d_in, const int* in_sizes, int n_in,
                              void* d_out, int out_size, void* d_ws, size_t ws_size,
                              hipStream_t stream) {
    const float* pred = (const float*)d_in[0];
    const float* gt   = (const float*)d_in[1];
    float* out        = (float*)d_out;
    unsigned short* Ppa = (unsigned short*)d_ws;
    unsigned short* Pgb = (unsigned short*)((char*)d_ws + WS_PGB);
    float* part         = (float*)((char*)d_ws + WS_PART);

    hipLaunchKernelGGL(pack_points, dim3(NPTS / 256), dim3(256), 0, stream,
                       pred, gt, Ppa, Pgb, out);
    hipLaunchKernelGGL(chamfer_bidi, dim3(NYR, NXB), dim3(BLOCK), 0, stream,
                       Ppa, Pgb, part);
    hipLaunchKernelGGL(chamfer_reduce, dim3(2 * NPTS / 1024), dim3(256), 0, stream,
                       part, out);
}

// Round 15
// 89.961 us; speedup vs baseline: 2.1345x; 2.1345x over previous
//
#include <hip/hip_runtime.h>

// Chamfer loss: pred (2048,8,3) vs gt (2048,8,3) fp32. N=16384 pts/side.
// out = mean(min_m d) + mean(min_n d); 8-corner group-mean == global mean.
//
// R18 = R16 RESTORED (verified best: total 90.3us, kernel ~34us, clean
// counters). R17's fused-bidi is falsified: two accumulator families in
// the 8-deep MFMA loop -> regalloc blowup (VGPR 256 real, 38MB scratch
// writes, occupancy 10%, 140us). Session ledger:
//  - fill (harness ws re-poison): 42us @ 80% HBM - incompressible.
//  - rowmin ~34us: survived atomic-removal, LDS-share (L2 512->64MB),
//    spill-proofing, flush inversion, arch-VGPR asm; residual ~3-4x
//    model gap consistent only with post-fill DPM clock throttle.
// Structure (all pieces individually verified):
//  - unidirectional two-pass (dir=blockIdx.z), bf16 3-way-split
//    K-packing (absmax 0.0 since R5): acc = -d2/2 per MFMA.
//  - XW=128 (af[8]+rmax[8]); B shared by 4 waves via 8KB double-
//    buffered LDS chunks, loads issued post-barrier (T14).
//  - kg-major fragment layout -> 1KB-contiguous wave loads, 2-lane/bank
//    LDS reads (conflict-free).
//  - inline-asm MFMA pairs (R15 hazard padding) - arch-VGPR forced.
//  - one DPP ror-max flush per wave; coalesced partial stores; no
//    atomics in hot path; 32-block reduce (never single-block tail).

#define NPTS   16384
#define BLOCK  256            // 4 waves
#define XW     128            // x-points per wave (8 tiles, af in 32 VGPR)
#define XCH    512            // x-points per block (32 tiles)
#define NXB    (NPTS / XCH)   // 32
#define YRNG   1024           // y-points per block (64 tiles)
#define NYR    (NPTS / YRNG)  // 16
#define CHT    8              // y-tiles per LDS chunk (8 KB)
#define NCH    (YRNG / (CHT * 16))  // 8 chunks
#define ONEBF  0x3F80         // bf16 1.0

// ws: [0,4MB) packed Ppa|Ppb|Pga|Pgb (1MB each) | [4MB,6MB) part[32][NPTS]
//   slices 0..15 = pred row-min partials (yr), 16..31 = gt (16+yr)
#define WS_PPB  (1u << 20)
#define WS_PGA  (2u << 20)
#define WS_PGB  (3u << 20)
#define WS_PART (4u << 20)

typedef __attribute__((ext_vector_type(8))) short bf16x8;
typedef __attribute__((ext_vector_type(4))) float f32x4;
typedef __attribute__((ext_vector_type(4))) unsigned int u32x4;

__device__ inline unsigned short f2bf(float f) {  // fp32 -> bf16 RNE
    unsigned int u = __float_as_uint(f);
    return (unsigned short)((u + 0x7FFFu + ((u >> 16) & 1u)) >> 16);
}
__device__ inline float bf2f(unsigned short h) {
    return __uint_as_float((unsigned int)h << 16);
}
__device__ inline void split3(float v, unsigned short* s) {
    unsigned short h = f2bf(v);  float r = v - bf2f(h);
    unsigned short m = f2bf(r);  r -= bf2f(m);
    s[0] = h; s[1] = m; s[2] = f2bf(r);
}

// K-slot map (identical order on A and B rows => lane->K bijection cancels):
//   s=c*3+d, c<6: cross combos (i,j)=(h,h)(h,m)(m,h)(h,l)(m,m)(l,h)
//   s=18..20: a=split3(-|p|^2/2), b=1 ; s=21..23: a=1, b=split3(-|p|^2/2)
//   s=24..31: 0   => S[r][c] = x.y - |x|^2/2 - |y|^2/2 = -d2/2
__device__ inline void build_rows(const float p[3], unsigned short* a,
                                  unsigned short* b) {
    const int CI[6] = {0, 0, 1, 0, 1, 2};
    const int CJ[6] = {0, 1, 0, 2, 1, 0};
    unsigned short xs[3][3], nn[3], t[3];
#pragma unroll
    for (int d = 0; d < 3; ++d) {
        split3(p[d], t);
        xs[0][d] = t[0]; xs[1][d] = t[1]; xs[2][d] = t[2];
    }
    split3(-0.5f * (p[0]*p[0] + p[1]*p[1] + p[2]*p[2]), nn);
#pragma unroll
    for (int c = 0; c < 6; ++c)
#pragma unroll
        for (int d = 0; d < 3; ++d) {
            a[c*3+d] = xs[CI[c]][d];
            b[c*3+d] = xs[CJ[c]][d];
        }
#pragma unroll
    for (int k = 0; k < 3; ++k) {
        a[18+k] = nn[k];  b[18+k] = ONEBF;
        a[21+k] = ONEBF;  b[21+k] = nn[k];
    }
#pragma unroll
    for (int k = 24; k < 32; ++k) { a[k] = 0; b[k] = 0; }
}

// Fragment-swizzled store (R12-verified): point i, K-chunk kg -> uint4 slot
// (i/16)*64 + kg*16 + (i%16); lane (col,kg) reads frag at slot
// tile*64 + kg*16 + col -> wave reads a contiguous 1KB line per instr.
__device__ inline void store_row_swz(uint4* dst4, int i, const unsigned short* s) {
    unsigned int w[16];
#pragma unroll
    for (int k = 0; k < 16; ++k)
        w[k] = (unsigned int)s[2*k] | ((unsigned int)s[2*k+1] << 16);
    const int base = (i >> 4) * 64 + (i & 15);
#pragma unroll
    for (int kgc = 0; kgc < 4; ++kgc)
        dst4[base + kgc * 16] = make_uint4(w[4*kgc], w[4*kgc+1],
                                           w[4*kgc+2], w[4*kgc+3]);
}

__global__ __launch_bounds__(256) void pack_points(
        const float* __restrict__ pred, const float* __restrict__ gt,
        unsigned short* __restrict__ Ppa, unsigned short* __restrict__ Ppb,
        unsigned short* __restrict__ Pga, unsigned short* __restrict__ Pgb,
        float* __restrict__ out) {
    const int i = blockIdx.x * 256 + threadIdx.x;
    if (i == 0) out[0] = 0.0f;  // replaces a memset dispatch
    if (i >= NPTS) return;
    float p[3] = {pred[3*i], pred[3*i+1], pred[3*i+2]};
    float q[3] = {gt[3*i],   gt[3*i+1],   gt[3*i+2]};
    unsigned short ra[32], rb[32];
    build_rows(p, ra, rb);
    store_row_swz(reinterpret_cast<uint4*>(Ppa), i, ra);
    store_row_swz(reinterpret_cast<uint4*>(Ppb), i, rb);
    build_rows(q, ra, rb);
    store_row_swz(reinterpret_cast<uint4*>(Pga), i, ra);
    store_row_swz(reinterpret_cast<uint4*>(Pgb), i, rb);
}

// DPP rotate-max within 16-lane rows (VALU pipe; verified R6-R16).
template <int CTRL>
__device__ inline float rormax(float v) {
    int t = __builtin_amdgcn_update_dpp(0, __float_as_int(v), CTRL, 0xF, 0xF,
                                        false);
    return fmaxf(v, __int_as_float(t));
}

__global__ __launch_bounds__(BLOCK, 1) void chamfer_rowmin(
        const unsigned short* __restrict__ Ppa,
        const unsigned short* __restrict__ Ppb,
        const unsigned short* __restrict__ Pga,
        const unsigned short* __restrict__ Pgb,
        float* __restrict__ part) {
    const int xb  = blockIdx.x;
    const int yr  = blockIdx.y;
    const int dir = blockIdx.z;
    const unsigned short* __restrict__ Ap = dir ? Pga : Ppa;  // rows = X side
    const unsigned short* __restrict__ Bp = dir ? Ppb : Pgb;  // cols = Y side
    const int tid = threadIdx.x;
    const int lane = tid & 63, w = tid >> 6;
    const int col = lane & 15, kg = lane >> 4;
    const int frag = kg * 16 + col;      // uint4 index of this lane's frag

    __shared__ uint4 buf[2][CHT * 64];   // 2 x 8 KB B double-buffer
    __shared__ float rowacc[XCH];        // 2 KB epilogue buffer

    // A-frags: wave's 8 x-tiles (each load = contiguous 1KB line)
    const uint4* ap = reinterpret_cast<const uint4*>(Ap);
    const int tile0 = xb * 32 + w * 8;
    u32x4 af[8];
#pragma unroll
    for (int xi = 0; xi < 8; ++xi)
        af[xi] = *reinterpret_cast<const u32x4*>(&ap[(tile0 + xi) * 64 + frag]);

    f32x4 rmax[8];
#pragma unroll
    for (int xi = 0; xi < 8; ++xi)
        rmax[xi] = (f32x4){-3.0e38f, -3.0e38f, -3.0e38f, -3.0e38f};

    const u32x4 zz = {0u, 0u, 0u, 0u};

    // B chunks: block's 4 waves SHARE each 8KB chunk via LDS.
    const uint4* bp = reinterpret_cast<const uint4*>(Bp) + (size_t)(yr * 64) * 64;
    uint4 s0 = bp[tid];                  // prologue: chunk 0 into regs
    uint4 s1 = bp[256 + tid];

#pragma unroll 1
    for (int c = 0; c < NCH; ++c) {
        // write staged chunk; single barrier per chunk (double buffer:
        // buf[c&1] was last read at iter c-2, all waves past bar(c-1))
        buf[c & 1][tid]       = s0;
        buf[c & 1][256 + tid] = s1;
        __syncthreads();
        if (c + 1 < NCH) {               // issue next chunk's loads now;
            s0 = bp[(c + 1) * 512 + tid];        // L2 latency hides under
            s1 = bp[(c + 1) * 512 + 256 + tid];  // this chunk's 64 MFMAs
        }
        const uint4* bb = buf[c & 1];
#pragma unroll
        for (int t = 0; t < CHT; t += 2) {
            u32x4 c0 = *reinterpret_cast<const u32x4*>(&bb[(t + 0) * 64 + frag]);
            u32x4 c1 = *reinterpret_cast<const u32x4*>(&bb[(t + 1) * 64 + frag]);
#pragma unroll
            for (int xi = 0; xi < 8; ++xi) {
                f32x4 A, B;
                // R15-verified: arch-VGPR-forced MFMA + hazard padding
                asm("s_nop 1\n\t"
                    "v_mfma_f32_16x16x32_bf16 %0, %2, %3, %5\n\t"
                    "v_mfma_f32_16x16x32_bf16 %1, %2, %4, %5\n\t"
                    "s_nop 7\n\t"
                    "s_nop 7\n\t"
                    "s_nop 3"
                    : "=&v"(A), "=&v"(B)
                    : "v"(af[xi]), "v"(c0), "v"(c1), "v"(zz));
                rmax[xi].x = fmaxf(fmaxf(A.x, B.x), rmax[xi].x);  // v_max3
                rmax[xi].y = fmaxf(fmaxf(A.y, B.y), rmax[xi].y);
                rmax[xi].z = fmaxf(fmaxf(A.z, B.z), rmax[xi].z);
                rmax[xi].w = fmaxf(fmaxf(A.w, B.w), rmax[xi].w);
            }
        }
        __syncthreads();  // all reads of buf[c&1] done before c+2 overwrite
    }

    // flush ONCE per wave: DPP ror-max over 16 cols, park in LDS,
    // one coalesced 2KB store per block.
#pragma unroll
    for (int xi = 0; xi < 8; ++xi) {
#pragma unroll
        for (int cc = 0; cc < 4; ++cc) {
            float v = rmax[xi][cc];
            v = rormax<0x121>(v);
            v = rormax<0x122>(v);
            v = rormax<0x124>(v);
            v = rormax<0x128>(v);
            if (col == 0)
                rowacc[w * XW + xi * 16 + kg * 4 + cc] = fmaxf(-2.0f * v, 0.0f);
        }
    }
    __syncthreads();
    float* dst = part + (size_t)(dir * NYR + yr) * NPTS + xb * XCH;
    dst[tid]       = rowacc[tid];
    dst[256 + tid] = rowacc[256 + tid];
}

__global__ __launch_bounds__(256) void chamfer_reduce(
        const float* __restrict__ part, float* __restrict__ out) {
    const int gid = blockIdx.x * 256 + threadIdx.x;  // 32 blocks x 256
    const int side = gid >> 12;                      // 4096 f32x4 per side
    const int idx4 = (gid & 4095) * 4;
    const float* base = part + (size_t)side * NYR * NPTS + idx4;
    float4 m = make_float4(3.0e38f, 3.0e38f, 3.0e38f, 3.0e38f);
#pragma unroll
    for (int c = 0; c < NYR; ++c) {
        float4 v = *reinterpret_cast<const float4*>(base + (size_t)c * NPTS);
        m.x = fminf(m.x, v.x); m.y = fminf(m.y, v.y);
        m.z = fminf(m.z, v.z); m.w = fminf(m.w, v.w);
    }
    float s = sqrtf(m.x) + sqrtf(m.y) + sqrtf(m.z) + sqrtf(m.w);
#pragma unroll
    for (int o = 32; o > 0; o >>= 1)
        s += __shfl_down(s, o, 64);
    if ((threadIdx.x & 63) == 0)
        atomicAdd(out, s * (1.0f / (float)NPTS));
}

extern "C" void kernel_launch(void* const* d_in, const int* in_sizes, int n_in,
                              void* d_out, int out_size, void* d_ws, size_t ws_size,
                              hipStream_t stream) {
    const float* pred = (const float*)d_in[0];
    const float* gt   = (const float*)d_in[1];
    float* out        = (float*)d_out;
    unsigned short* Ppa = (unsigned short*)d_ws;
    unsigned short* Ppb = (unsigned short*)((char*)d_ws + WS_PPB);
    unsigned short* Pga = (unsigned short*)((char*)d_ws + WS_PGA);
    unsigned short* Pgb = (unsigned short*)((char*)d_ws + WS_PGB);
    float* part         = (float*)((char*)d_ws + WS_PART);

    hipLaunchKernelGGL(pack_points, dim3(NPTS / 256), dim3(256), 0, stream,
                       pred, gt, Ppa, Ppb, Pga, Pgb, out);
    hipLaunchKernelGGL(chamfer_rowmin, dim3(NXB, NYR, 2), dim3(BLOCK), 0, stream,
                       Ppa, Ppb, Pga, Pgb, part);
    hipLaunchKernelGGL(chamfer_reduce, dim3(2 * NPTS / 1024), dim3(256), 0, stream,
                       part, out);
}